// Round 1
// baseline (30315.265 us; speedup 1.0000x reference)
//
#include <hip/hip_runtime.h>
#include <hip/hip_bf16.h>

#define EPSF 1e-8f

// ---------------------------------------------------------------------------
// conv1: image[512,1,28,28] * cw[256,1,9,9] + cb -> relu -> x bf16 [512,256,20,20]
// block: 256 threads, grid (512 b, 8 c-groups of 32)
// ---------------------------------------------------------------------------
__global__ void k_conv1(const float* __restrict__ img, const float* __restrict__ cw,
                        const float* __restrict__ cb, __hip_bfloat16* __restrict__ x)
{
    const int b  = blockIdx.x;
    const int c0 = blockIdx.y * 32;
    const int t  = threadIdx.x;
    __shared__ float simg[784];
    __shared__ float sw[32 * 81];
    for (int i = t; i < 784; i += 256) simg[i] = img[b * 784 + i];
    for (int i = t; i < 32 * 81; i += 256) sw[i] = cw[c0 * 81 + i];
    __syncthreads();
    for (int oi = t; oi < 32 * 400; oi += 256) {
        int cl = oi / 400;
        int hw = oi - cl * 400;
        int h = hw / 20, w = hw - h * 20;
        float acc = cb[c0 + cl];
        const float* wr = &sw[cl * 81];
        const float* ir = &simg[h * 28 + w];
        #pragma unroll
        for (int ky = 0; ky < 9; ++ky) {
            #pragma unroll
            for (int kx = 0; kx < 9; ++kx)
                acc += ir[ky * 28 + kx] * wr[ky * 9 + kx];
        }
        acc = fmaxf(acc, 0.f);
        x[(size_t)(b * 256 + c0 + cl) * 400 + hw] = __float2bfloat16(acc);
    }
}

// ---------------------------------------------------------------------------
// primary caps conv: x[512,256,20,20] * pw[256,256,9,9] stride2 + pcb
//   -> uraw f32 [512, 9216]  (layout == [b][oc][h2][w2], oc = caps*32+ch)
// block: 1024 threads = 256 oc * 4 q; thread owns 9 hw positions (q+4i)
// grid: 512 (b). LDS: 16 input channels staged per chunk (25.6 KB).
// ---------------------------------------------------------------------------
__global__ __launch_bounds__(1024) void k_conv2(const __hip_bfloat16* __restrict__ x,
                                                const float* __restrict__ pw,
                                                const float* __restrict__ pcb,
                                                float* __restrict__ uraw)
{
    const int b = blockIdx.x;
    const int t = threadIdx.x;
    const int oc = t >> 2;
    const int q  = t & 3;
    __shared__ float xs[16 * 400];
    float acc[9];
    #pragma unroll
    for (int i = 0; i < 9; ++i) acc[i] = 0.f;
    int offp[9];
    #pragma unroll
    for (int i = 0; i < 9; ++i) {
        int hw = q + 4 * i;
        int h = hw / 6, w = hw - h * 6;
        offp[i] = (2 * h) * 20 + 2 * w;
    }
    for (int icc = 0; icc < 16; ++icc) {
        __syncthreads();
        for (int idx = t; idx < 6400; idx += 1024)
            xs[idx] = __bfloat162float(x[(size_t)(b * 256 + icc * 16) * 400 + idx]);
        __syncthreads();
        for (int cc = 0; cc < 16; ++cc) {
            const float* wr = pw + (size_t)(oc * 256 + icc * 16 + cc) * 81;
            const int xb = cc * 400;
            #pragma unroll
            for (int ky = 0; ky < 9; ++ky) {
                const float w0 = wr[ky * 9 + 0], w1 = wr[ky * 9 + 1], w2 = wr[ky * 9 + 2];
                const float w3 = wr[ky * 9 + 3], w4 = wr[ky * 9 + 4], w5 = wr[ky * 9 + 5];
                const float w6 = wr[ky * 9 + 6], w7 = wr[ky * 9 + 7], w8 = wr[ky * 9 + 8];
                const int rb = xb + ky * 20;
                #pragma unroll
                for (int i = 0; i < 9; ++i) {
                    const float* xp = &xs[rb + offp[i]];   // even index -> 8B aligned
                    float2 a0 = *(const float2*)(xp + 0);
                    float2 a1 = *(const float2*)(xp + 2);
                    float2 a2 = *(const float2*)(xp + 4);
                    float2 a3 = *(const float2*)(xp + 6);
                    float  a4 = xp[8];
                    acc[i] += w0 * a0.x + w1 * a0.y + w2 * a1.x + w3 * a1.y
                            + w4 * a2.x + w5 * a2.y + w6 * a3.x + w7 * a3.y + w8 * a4;
                }
            }
        }
    }
    const float bias = pcb[oc];
    #pragma unroll
    for (int i = 0; i < 9; ++i) {
        int hw = q + 4 * i;
        uraw[(size_t)b * 9216 + oc * 36 + hw] = acc[i] + bias;
    }
}

// ---------------------------------------------------------------------------
// squash groups of 8 (in place): u[g*8..g*8+7]
// ---------------------------------------------------------------------------
__global__ void k_squash_u(float* __restrict__ u, int ngroups)
{
    int g = blockIdx.x * blockDim.x + threadIdx.x;
    if (g >= ngroups) return;
    float4* p = (float4*)(u + (size_t)g * 8);
    float4 a = p[0], c = p[1];
    float sq = a.x * a.x + a.y * a.y + a.z * a.z + a.w * a.w
             + c.x * c.x + c.y * c.y + c.z * c.z + c.w * c.w;
    float scale = (sq / (1.f + sq)) / sqrtf(sq + EPSF);
    a.x *= scale; a.y *= scale; a.z *= scale; a.w *= scale;
    c.x *= scale; c.y *= scale; c.z *= scale; c.w *= scale;
    p[0] = a; p[1] = c;
}

// ---------------------------------------------------------------------------
// routing iteration (u_hat recomputed, b_ij never stored: q = sum_o uh*vsum).
// grid 512 (b), block 256. One launch per iteration (0,1,2).
// iter==2 also writes obj_vectors, y_prob, masked decoder input.
// ---------------------------------------------------------------------------
#define UHS 161   // padded stride for uh tile (bank-conflict break)
__global__ void k_route(const float* __restrict__ u, const float* __restrict__ W,
                        const float* __restrict__ vsum_io, float* __restrict__ vsum_out,
                        const int* __restrict__ label,
                        float* __restrict__ obj, float* __restrict__ yprob,
                        float* __restrict__ masked, int iter)
{
    const int b = blockIdx.x;
    const int t = threadIdx.x;
    __shared__ float su[512];          // u chunk: 64 r x 8
    __shared__ float suh[64 * UHS];    // u_hat chunk: 64 r x 160 (padded)
    __shared__ float sc[64 * 10];      // q then c (softmax over j)
    __shared__ float svs[160];         // running v-sum
    if (t < 160) svs[t] = (iter > 0) ? vsum_io[b * 160 + t] : 0.f;
    float sacc = 0.f;                  // s_j accumulator for (j,o) = (t>>4, t&15)
    const int rl = t >> 2, oq = t & 3;
    for (int rc = 0; rc < 18; ++rc) {
        const int r0 = rc * 64;
        __syncthreads();
        for (int idx = t; idx < 512; idx += 256)
            su[idx] = u[(size_t)b * 9216 + r0 * 8 + idx];
        __syncthreads();
        float uu[8];
        #pragma unroll
        for (int c = 0; c < 8; ++c) uu[c] = su[rl * 8 + c];
        float uh[10][4];
        const float* wb = W + (size_t)(r0 + rl) * 1280 + oq * 32;
        #pragma unroll
        for (int j = 0; j < 10; ++j) {
            const float4* wj = (const float4*)(wb + j * 128);
            #pragma unroll
            for (int oo = 0; oo < 4; ++oo) {
                float4 wA = wj[oo * 2], wB = wj[oo * 2 + 1];
                float s = wA.x * uu[0] + wA.y * uu[1] + wA.z * uu[2] + wA.w * uu[3]
                        + wB.x * uu[4] + wB.y * uu[5] + wB.z * uu[6] + wB.w * uu[7];
                uh[j][oo] = s;
                suh[rl * UHS + j * 16 + oq * 4 + oo] = s;
            }
        }
        if (iter > 0) {
            #pragma unroll
            for (int j = 0; j < 10; ++j) {
                float qp = uh[j][0] * svs[j * 16 + oq * 4 + 0]
                         + uh[j][1] * svs[j * 16 + oq * 4 + 1]
                         + uh[j][2] * svs[j * 16 + oq * 4 + 2]
                         + uh[j][3] * svs[j * 16 + oq * 4 + 3];
                qp += __shfl_xor(qp, 1);
                qp += __shfl_xor(qp, 2);
                if (oq == 0) sc[rl * 10 + j] = qp;
            }
        }
        __syncthreads();
        if (t < 64) {
            if (iter == 0) {
                for (int j = 0; j < 10; ++j) sc[t * 10 + j] = 0.1f;
            } else {
                float m = -1e30f;
                for (int j = 0; j < 10; ++j) m = fmaxf(m, sc[t * 10 + j]);
                float e[10]; float ssum = 0.f;
                for (int j = 0; j < 10; ++j) { e[j] = expf(sc[t * 10 + j] - m); ssum += e[j]; }
                float inv = 1.f / ssum;
                for (int j = 0; j < 10; ++j) sc[t * 10 + j] = e[j] * inv;
            }
        }
        __syncthreads();
        if (t < 160) {
            const int j = t >> 4;
            for (int r = 0; r < 64; ++r)
                sacc += sc[r * 10 + j] * suh[r * UHS + t];
        }
    }
    if (t < 160) {
        const int j = t >> 4, o = t & 15;
        float sq = sacc * sacc;
        sq += __shfl_xor(sq, 1); sq += __shfl_xor(sq, 2);
        sq += __shfl_xor(sq, 4); sq += __shfl_xor(sq, 8);
        float v = sacc * (sq / (1.f + sq)) / sqrtf(sq + EPSF);
        vsum_out[b * 160 + t] = svs[t] + v;
        if (iter == 2) {
            obj[b * 160 + t] = v;
            float vv = v * v;
            vv += __shfl_xor(vv, 1); vv += __shfl_xor(vv, 2);
            vv += __shfl_xor(vv, 4); vv += __shfl_xor(vv, 8);
            if (o == 0) yprob[b * 10 + j] = sqrtf(vv + EPSF);
            masked[b * 160 + t] = (label[b] == j) ? v : 0.f;
        }
    }
}

// ---------------------------------------------------------------------------
// decoder GEMM: C[m,n] = act(bias[n] + sum_k A[m,k]*Wt[n,k]); M=512 fixed.
// 32x32 tiles, block 256, act: 0=relu, 1=sigmoid. K must be mult of 32.
// ---------------------------------------------------------------------------
__global__ void k_mlp(const float* __restrict__ A, const float* __restrict__ Wt,
                      const float* __restrict__ bias, float* __restrict__ C,
                      int N, int K, int act)
{
    const int m0 = blockIdx.x * 32;
    const int n0 = blockIdx.y * 32;
    const int t  = threadIdx.x;
    const int tn = t & 31, tg = t >> 5;
    __shared__ float As[32][33];
    __shared__ float Ws[32][33];
    float acc[4] = {0.f, 0.f, 0.f, 0.f};
    for (int k0 = 0; k0 < K; k0 += 32) {
        __syncthreads();
        for (int idx = t; idx < 1024; idx += 256) {
            int rr = idx >> 5, kk = idx & 31;
            As[rr][kk] = A[(size_t)(m0 + rr) * K + k0 + kk];
            int n = n0 + rr;
            Ws[rr][kk] = (n < N) ? Wt[(size_t)n * K + k0 + kk] : 0.f;
        }
        __syncthreads();
        #pragma unroll 8
        for (int kk = 0; kk < 32; ++kk) {
            float bv = Ws[tn][kk];
            #pragma unroll
            for (int i = 0; i < 4; ++i)
                acc[i] += As[tg * 4 + i][kk] * bv;
        }
    }
    int n = n0 + tn;
    if (n < N) {
        float bs = bias[n];
        #pragma unroll
        for (int i = 0; i < 4; ++i) {
            float vv = acc[i] + bs;
            vv = (act == 0) ? fmaxf(vv, 0.f) : 1.f / (1.f + expf(-vv));
            C[(size_t)(m0 + tg * 4 + i) * N + n] = vv;
        }
    }
}

// ---------------------------------------------------------------------------
extern "C" void kernel_launch(void* const* d_in, const int* in_sizes, int n_in,
                              void* d_out, int out_size, void* d_ws, size_t ws_size,
                              hipStream_t stream)
{
    const float* image  = (const float*)d_in[0];
    const int*   label  = (const int*)  d_in[1];
    const float* conv_w = (const float*)d_in[2];
    const float* conv_b = (const float*)d_in[3];
    const float* pc_w   = (const float*)d_in[4];
    const float* pc_b   = (const float*)d_in[5];
    const float* Wrt    = (const float*)d_in[6];
    const float* dw1 = (const float*)d_in[7];
    const float* db1 = (const float*)d_in[8];
    const float* dw2 = (const float*)d_in[9];
    const float* db2 = (const float*)d_in[10];
    const float* dw3 = (const float*)d_in[11];
    const float* db3 = (const float*)d_in[12];
    float* out = (float*)d_out;

    char* wsp = (char*)d_ws;
    __hip_bfloat16* x = (__hip_bfloat16*)wsp; wsp += (size_t)512 * 256 * 400 * 2; // 104.9 MB
    float* u      = (float*)wsp; wsp += (size_t)4718592 * 4;                      // 18.9 MB
    float* vsum   = (float*)wsp; wsp += (size_t)81920 * 4;
    float* masked = (float*)wsp; wsp += (size_t)81920 * 4;
    float* h1     = (float*)wsp; wsp += (size_t)262144 * 4;
    float* h2     = (float*)wsp; wsp += (size_t)524288 * 4;

    float* obj   = out;            // [512,10,16,1]
    float* recon = out + 81920;    // [512,1,28,28]
    float* yprob = out + 483328;   // [512,10]

    k_conv1<<<dim3(512, 8), 256, 0, stream>>>(image, conv_w, conv_b, x);
    k_conv2<<<512, 1024, 0, stream>>>(x, pc_w, pc_b, u);
    k_squash_u<<<2304, 256, 0, stream>>>(u, 589824);
    for (int it = 0; it < 3; ++it)
        k_route<<<512, 256, 0, stream>>>(u, Wrt, vsum, vsum, label, obj, yprob, masked, it);
    k_mlp<<<dim3(16, 16), 256, 0, stream>>>(masked, dw1, db1, h1, 512, 160, 0);
    k_mlp<<<dim3(16, 32), 256, 0, stream>>>(h1, dw2, db2, h2, 1024, 512, 0);
    k_mlp<<<dim3(16, 25), 256, 0, stream>>>(h2, dw3, db3, recon, 784, 1024, 1);
}

// Round 3
// 1697.032 us; speedup vs baseline: 17.8637x; 17.8637x over previous
//
#include <hip/hip_runtime.h>
#include <hip/hip_bf16.h>

#define EPSF 1e-8f

typedef __attribute__((ext_vector_type(8))) short short8v;
typedef __attribute__((ext_vector_type(4))) float float4v;

// ---------------------------------------------------------------------------
// Bw transform: pc_w f32 [256oc][256ic][81] -> Bw bf16 [81][256oc][256ic]
// ---------------------------------------------------------------------------
__global__ void k_bw(const float* __restrict__ pw, __hip_bfloat16* __restrict__ Bw)
{
    const int oc = blockIdx.x;
    const int ic = threadIdx.x;
    const float* src = pw + ((size_t)oc * 256 + ic) * 81;
    #pragma unroll
    for (int k = 0; k < 81; ++k)
        Bw[(size_t)k * 65536 + oc * 256 + ic] = __float2bfloat16(src[k]);
}

// ---------------------------------------------------------------------------
// conv1: image[512,1,28,28] * cw[256,1,9,9] + cb -> relu
//   -> x_t bf16 [b][icc=8][pos=400][64B unit, slot-XOR-permuted]
//   pos = h*20 + (w&1)*10 + (w>>1)   (de-interleaved columns)
//   unit byte: ((slot ^ ((pos>>1)&3))<<4) + ic8*2,  c = icc*32 + slot*8 + ic8
// block = b, 256 threads = c. Image reads wave-uniform -> s_loads.
// ---------------------------------------------------------------------------
__global__ __launch_bounds__(256) void k_conv1(const float* __restrict__ img,
                                               const float* __restrict__ cw,
                                               const float* __restrict__ cb,
                                               __hip_bfloat16* __restrict__ xt)
{
    const int b = blockIdx.x;
    const int c = threadIdx.x;
    float wreg[81];
    const float* wp = cw + c * 81;
    #pragma unroll
    for (int k = 0; k < 81; ++k) wreg[k] = wp[k];
    const float bias = cb[c];
    const float* ib = img + b * 784;
    const int icc = c >> 5, slot = (c >> 3) & 3, ic8 = c & 7;
    char* xbase = (char*)xt + ((size_t)b * 8 + icc) * 25600;
    for (int h = 0; h < 20; ++h) {
        for (int w = 0; w < 20; ++w) {
            float acc = bias;
            #pragma unroll
            for (int ky = 0; ky < 9; ++ky) {
                #pragma unroll
                for (int kx = 0; kx < 9; ++kx)
                    acc = fmaf(ib[(h + ky) * 28 + w + kx], wreg[ky * 9 + kx], acc);
            }
            acc = fmaxf(acc, 0.f);
            int pos = h * 20 + (w & 1) * 10 + (w >> 1);
            int off = pos * 64 + ((slot ^ ((pos >> 1) & 3)) << 4) + ic8 * 2;
            *(__hip_bfloat16*)(xbase + off) = __float2bfloat16(acc);
        }
    }
}

// ---------------------------------------------------------------------------
// conv2 via MFMA: u[b][oc*36+hw] = sum_{ic,ky,kx} x * w + pcb
// grid 256 (2 b each), 512 thr = 8 waves (wr = b-local, wc = 64-oc group).
// K-loop: icc(8) x kidx(81), K=32 per MFMA step.
// A frag: row=hw (lane&15), k-chunk=slot=lane>>4 (8 ch). B frag: n=oc=lane&15.
// ---------------------------------------------------------------------------
__global__ __launch_bounds__(512) void k_conv2(const __hip_bfloat16* __restrict__ xt,
                                               const __hip_bfloat16* __restrict__ Bw,
                                               const float* __restrict__ pcb,
                                               float* __restrict__ u)
{
    const int b0 = blockIdx.x * 2;
    const int t = threadIdx.x;
    const int lane = t & 63, wid = t >> 6;
    const int wr = wid >> 2, wc = wid & 3;
    const int r16 = lane & 15, slot = lane >> 4;

    __shared__ float4v xs4[3200];   // 51200 B: [wr][1600 units]
    char* xs = (char*)xs4;

    int lc[3];
    #pragma unroll
    for (int mt = 0; mt < 3; ++mt) {
        int hw = mt * 16 + r16;
        if (hw >= 36) hw = 0;
        int h = hw / 6, w = hw - h * 6;
        lc[mt] = 40 * h + w;
    }

    float4v acc[3][4];
    #pragma unroll
    for (int mt = 0; mt < 3; ++mt)
        #pragma unroll
        for (int nt = 0; nt < 4; ++nt)
            acc[mt][nt] = (float4v){0.f, 0.f, 0.f, 0.f};

    for (int icc = 0; icc < 8; ++icc) {
        __syncthreads();
        #pragma unroll
        for (int k = 0; k < 7; ++k) {
            int uidx = t + k * 512;
            if (uidx < 3200) {
                int bb = (uidx >= 1600) ? 1 : 0;
                int off = uidx - bb * 1600;
                const float4v* src = (const float4v*)(xt + ((size_t)(b0 + bb) * 8 + icc) * 12800);
                xs4[uidx] = src[off];
            }
        }
        __syncthreads();

        const char* xw = xs + wr * 25600;
        size_t bcol = (size_t)(wc * 64 + r16) * 256 + icc * 32 + slot * 8;

        #pragma unroll 3
        for (int kidx = 0; kidx < 81; ++kidx) {
            int ky = kidx / 9, kx = kidx - ky * 9;
            int scalK = 20 * ky + 10 * (kx & 1) + (kx >> 1);
            short8v a[3];
            #pragma unroll
            for (int mt = 0; mt < 3; ++mt) {
                int pos = lc[mt] + scalK;
                int off = pos * 64 + (((slot ^ (pos >> 1)) & 3) << 4);
                a[mt] = *(const short8v*)(xw + off);
            }
            const __hip_bfloat16* bp = Bw + (size_t)kidx * 65536 + bcol;
            short8v bv[4];
            #pragma unroll
            for (int nt = 0; nt < 4; ++nt)
                bv[nt] = *(const short8v*)(bp + nt * 4096);
            #pragma unroll
            for (int mt = 0; mt < 3; ++mt)
                #pragma unroll
                for (int nt = 0; nt < 4; ++nt)
                    acc[mt][nt] = __builtin_amdgcn_mfma_f32_16x16x32_bf16(a[mt], bv[nt], acc[mt][nt], 0, 0, 0);
        }
    }

    // epilogue: D row(hw) = slot*4+i, col(oc) = r16
    const int b = b0 + wr;
    #pragma unroll
    for (int mt = 0; mt < 3; ++mt) {
        int hwb = mt * 16 + slot * 4;
        if (hwb < 36) {
            #pragma unroll
            for (int nt = 0; nt < 4; ++nt) {
                int oc = wc * 64 + nt * 16 + r16;
                float pb = pcb[oc];
                float4v v = acc[mt][nt];
                v.x += pb; v.y += pb; v.z += pb; v.w += pb;
                *(float4v*)(u + (size_t)b * 9216 + oc * 36 + hwb) = v;
            }
        }
    }
}

// ---------------------------------------------------------------------------
// squash groups of 8 (in place)
// ---------------------------------------------------------------------------
__global__ void k_squash_u(float* __restrict__ u, int ngroups)
{
    int g = blockIdx.x * blockDim.x + threadIdx.x;
    if (g >= ngroups) return;
    float4v* p = (float4v*)(u + (size_t)g * 8);
    float4v a = p[0], c = p[1];
    float sq = a.x * a.x + a.y * a.y + a.z * a.z + a.w * a.w
             + c.x * c.x + c.y * c.y + c.z * c.z + c.w * c.w;
    float scale = (sq / (1.f + sq)) / sqrtf(sq + EPSF);
    a *= scale; c *= scale;
    p[0] = a; p[1] = c;
}

// ---------------------------------------------------------------------------
// routing iteration: grid (72 r-chunks of 16, 16 b-chunks of 32), 256 thr.
// W chunk f32 in LDS (80KB, XOR-swizzled 16B units). wave = one b per b-iter.
// partial s_j -> shfl-reduce over rl -> atomicAdd global s[b][160].
// ---------------------------------------------------------------------------
__global__ __launch_bounds__(256) void k_route3(const float* __restrict__ u,
                                                const float* __restrict__ W,
                                                const float* __restrict__ vsum,
                                                float* __restrict__ s, int iter)
{
    const int r0 = blockIdx.x * 16;
    const int b0 = blockIdx.y * 32;
    const int t = threadIdx.x;
    const int oq = t & 3, rl = (t >> 2) & 15, bl = t >> 6;

    __shared__ alignas(16) float Wl[16 * 160 * 8];  // 80KB, swizzled

    // stage: 5120 float4 units; unit' = rl*320 + (rest ^ (rl&7))
    for (int e = t; e < 5120; e += 256) {
        int rl_ = e / 320;
        int rest = e - rl_ * 320;
        float4v val = *(const float4v*)(W + (size_t)(r0 + rl_) * 1280 + rest * 4);
        *(float4v*)(Wl + ((size_t)rl_ * 320 + (rest ^ (rl_ & 7))) * 4) = val;
    }
    __syncthreads();

    const int m = rl & 7;
    int xo[8];
    #pragma unroll
    for (int z = 0; z < 8; ++z) xo[z] = (z ^ m) * 16;
    const char* wbase = (const char*)Wl + ((size_t)rl * 320 + oq * 8) * 16;

    for (int bb = 0; bb < 8; ++bb) {
        const int b = b0 + bb * 4 + bl;
        const float4v* up = (const float4v*)(u + (size_t)b * 9216 + (r0 + rl) * 8);
        float4v u0 = up[0], u1 = up[1];

        float uh[10][4];
        #pragma unroll
        for (int j = 0; j < 10; ++j) {
            const char* pj = wbase + j * 512;
            #pragma unroll
            for (int oo = 0; oo < 4; ++oo) {
                float4v wlo = *(const float4v*)(pj + xo[oo * 2]);
                float4v whi = *(const float4v*)(pj + xo[oo * 2 + 1]);
                uh[j][oo] = wlo.x * u0.x + wlo.y * u0.y + wlo.z * u0.z + wlo.w * u0.w
                          + whi.x * u1.x + whi.y * u1.y + whi.z * u1.z + whi.w * u1.w;
            }
        }

        float cj[10];
        if (iter > 0) {
            float q[10];
            #pragma unroll
            for (int j = 0; j < 10; ++j) {
                float4v vj = *(const float4v*)(vsum + (size_t)b * 160 + j * 16 + oq * 4);
                float qp = uh[j][0] * vj.x + uh[j][1] * vj.y + uh[j][2] * vj.z + uh[j][3] * vj.w;
                qp += __shfl_xor(qp, 1);
                qp += __shfl_xor(qp, 2);
                q[j] = qp;
            }
            float mx = q[0];
            #pragma unroll
            for (int j = 1; j < 10; ++j) mx = fmaxf(mx, q[j]);
            float ssum = 0.f;
            #pragma unroll
            for (int j = 0; j < 10; ++j) { cj[j] = __expf(q[j] - mx); ssum += cj[j]; }
            float inv = 1.f / ssum;
            #pragma unroll
            for (int j = 0; j < 10; ++j) cj[j] *= inv;
        } else {
            #pragma unroll
            for (int j = 0; j < 10; ++j) cj[j] = 0.1f;
        }

        #pragma unroll
        for (int j = 0; j < 10; ++j)
            #pragma unroll
            for (int oo = 0; oo < 4; ++oo) {
                float v = cj[j] * uh[j][oo];
                v += __shfl_xor(v, 4);
                v += __shfl_xor(v, 8);
                v += __shfl_xor(v, 16);
                v += __shfl_xor(v, 32);
                uh[j][oo] = v;
            }
        if (rl == 0) {
            #pragma unroll
            for (int j = 0; j < 10; ++j)
                #pragma unroll
                for (int oo = 0; oo < 4; ++oo)
                    atomicAdd(&s[(size_t)b * 160 + j * 16 + oq * 4 + oo], uh[j][oo]);
        }
    }
}

// ---------------------------------------------------------------------------
// finish: squash s -> v, vsum += v, zero s; iter==2 writes outputs
// ---------------------------------------------------------------------------
__global__ void k_finish(float* __restrict__ s, float* __restrict__ vsum,
                         const int* __restrict__ label, float* __restrict__ obj,
                         float* __restrict__ yprob, float* __restrict__ masked, int iter)
{
    const int b = blockIdx.x, t = threadIdx.x;
    if (t < 160) {
        float sv = s[b * 160 + t];
        float sq = sv * sv;
        sq += __shfl_xor(sq, 1); sq += __shfl_xor(sq, 2);
        sq += __shfl_xor(sq, 4); sq += __shfl_xor(sq, 8);
        float v = sv * (sq / (1.f + sq)) / sqrtf(sq + EPSF);
        float pv = (iter > 0) ? vsum[b * 160 + t] : 0.f;
        vsum[b * 160 + t] = pv + v;
        s[b * 160 + t] = 0.f;
        if (iter == 2) {
            obj[b * 160 + t] = v;
            float vv = v * v;
            vv += __shfl_xor(vv, 1); vv += __shfl_xor(vv, 2);
            vv += __shfl_xor(vv, 4); vv += __shfl_xor(vv, 8);
            int j = t >> 4;
            if ((t & 15) == 0) yprob[b * 10 + j] = sqrtf(vv + EPSF);
            masked[b * 160 + t] = (label[b] == j) ? v : 0.f;
        }
    }
}

// ---------------------------------------------------------------------------
// decoder GEMM: C[m,n] = act(bias[n] + sum_k A[m,k]*Wt[n,k]); M=512.
// ---------------------------------------------------------------------------
__global__ void k_mlp(const float* __restrict__ A, const float* __restrict__ Wt,
                      const float* __restrict__ bias, float* __restrict__ C,
                      int N, int K, int act)
{
    const int m0 = blockIdx.x * 32;
    const int n0 = blockIdx.y * 32;
    const int t  = threadIdx.x;
    const int tn = t & 31, tg = t >> 5;
    __shared__ float As[32][33];
    __shared__ float Ws[32][33];
    float acc[4] = {0.f, 0.f, 0.f, 0.f};
    for (int k0 = 0; k0 < K; k0 += 32) {
        __syncthreads();
        for (int idx = t; idx < 1024; idx += 256) {
            int rr = idx >> 5, kk = idx & 31;
            As[rr][kk] = A[(size_t)(m0 + rr) * K + k0 + kk];
            int n = n0 + rr;
            Ws[rr][kk] = (n < N) ? Wt[(size_t)n * K + k0 + kk] : 0.f;
        }
        __syncthreads();
        #pragma unroll 8
        for (int kk = 0; kk < 32; ++kk) {
            float bv = Ws[tn][kk];
            #pragma unroll
            for (int i = 0; i < 4; ++i)
                acc[i] += As[tg * 4 + i][kk] * bv;
        }
    }
    int n = n0 + tn;
    if (n < N) {
        float bs = bias[n];
        #pragma unroll
        for (int i = 0; i < 4; ++i) {
            float vv = acc[i] + bs;
            vv = (act == 0) ? fmaxf(vv, 0.f) : 1.f / (1.f + expf(-vv));
            C[(size_t)(m0 + tg * 4 + i) * N + n] = vv;
        }
    }
}

// ---------------------------------------------------------------------------
extern "C" void kernel_launch(void* const* d_in, const int* in_sizes, int n_in,
                              void* d_out, int out_size, void* d_ws, size_t ws_size,
                              hipStream_t stream)
{
    const float* image  = (const float*)d_in[0];
    const int*   label  = (const int*)  d_in[1];
    const float* conv_w = (const float*)d_in[2];
    const float* conv_b = (const float*)d_in[3];
    const float* pc_w   = (const float*)d_in[4];
    const float* pc_b   = (const float*)d_in[5];
    const float* Wrt    = (const float*)d_in[6];
    const float* dw1 = (const float*)d_in[7];
    const float* db1 = (const float*)d_in[8];
    const float* dw2 = (const float*)d_in[9];
    const float* db2 = (const float*)d_in[10];
    const float* dw3 = (const float*)d_in[11];
    const float* db3 = (const float*)d_in[12];
    float* out = (float*)d_out;

    char* p = (char*)d_ws;
    __hip_bfloat16* xt = (__hip_bfloat16*)p; p += 104857600;
    float* u      = (float*)p; p += 18874368;
    __hip_bfloat16* Bw = (__hip_bfloat16*)p; p += 10616832;
    float* s      = (float*)p; p += 327680;
    float* vsum   = (float*)p; p += 327680;
    float* masked = (float*)p; p += 327680;
    float* h1     = (float*)p; p += 1048576;
    float* h2     = (float*)p; p += 2097152;

    float* obj   = out;            // [512,10,16,1]
    float* recon = out + 81920;    // [512,1,28,28]
    float* yprob = out + 483328;   // [512,10]

    hipMemsetAsync(s, 0, 327680, stream);
    k_bw<<<256, 256, 0, stream>>>(pc_w, Bw);
    k_conv1<<<512, 256, 0, stream>>>(image, conv_w, conv_b, xt);
    k_conv2<<<256, 512, 0, stream>>>(xt, Bw, pc_b, u);
    k_squash_u<<<2304, 256, 0, stream>>>(u, 589824);
    for (int it = 0; it < 3; ++it) {
        k_route3<<<dim3(72, 16), 256, 0, stream>>>(u, Wrt, vsum, s, it);
        k_finish<<<512, 192, 0, stream>>>(s, vsum, label, obj, yprob, masked, it);
    }
    k_mlp<<<dim3(16, 16), 256, 0, stream>>>(masked, dw1, db1, h1, 512, 160, 0);
    k_mlp<<<dim3(16, 32), 256, 0, stream>>>(h1, dw2, db2, h2, 1024, 512, 0);
    k_mlp<<<dim3(16, 25), 256, 0, stream>>>(h2, dw3, db3, recon, 784, 1024, 1);
}